// Round 5
// baseline (507.820 us; speedup 1.0000x reference)
//
#include <hip/hip_runtime.h>
#include <hip/hip_bf16.h>

#define M_CH 2
#define J_F 2000
#define I_F 2049
#define K_B 8
#define N_IT 5
#define NMF_EPS 1e-20f
#define IP_EPS 1e-20f
#define JCH 50      // j-chunks for D partials
#define JCHSZ 40    // 50*40 = 2000 exactly
#define PJT 50      // j-tiles in P kernel
#define PJSZ 40     // 50*40 = 2000 exactly
#define IB 2304     // 9*256 padded i range

// ---------------- init: T[n][i][k], V[n][k][j], W[i] = eye ----------------
__global__ void k_init(const float* __restrict__ T0, const float* __restrict__ V0,
                       float* __restrict__ T, float* __restrict__ V, float* __restrict__ W) {
  int t = blockIdx.x * blockDim.x + threadIdx.x;
  int stride = gridDim.x * blockDim.x;
  for (int idx = t; idx < 2 * I_F * K_B; idx += stride) {
    int n = idx / (I_F * K_B);
    int r = idx % (I_F * K_B);
    int i = r / K_B, k = r % K_B;
    T[idx] = T0[(i * K_B + k) * M_CH + n];
  }
  for (int idx = t; idx < 2 * K_B * J_F; idx += stride) {
    int n = idx / (K_B * J_F);
    int r = idx % (K_B * J_F);
    int k = r / J_F, j = r % J_F;
    V[idx] = V0[(k * J_F + j) * M_CH + n];
  }
  for (int i = t; i < I_F; i += stride) {
    W[i * 8 + 0] = 1.f; W[i * 8 + 1] = 0.f; W[i * 8 + 2] = 0.f; W[i * 8 + 3] = 0.f;
    W[i * 8 + 4] = 0.f; W[i * 8 + 5] = 0.f; W[i * 8 + 6] = 1.f; W[i * 8 + 7] = 0.f;
  }
}

// ---- P[n][j][i] = |Y[i,n,j]|^2 + lane-local T partials; one n per z-block ----
__global__ __launch_bounds__(256) void k_P_T(const float2* __restrict__ X,
                                             const float* __restrict__ W,
                                             const float* __restrict__ T,
                                             const float* __restrict__ V,
                                             float* __restrict__ P,
                                             float* __restrict__ Tpart) {
  __shared__ float Vl[K_B][PJSZ];
  const int n = blockIdx.z;
  const int tid = threadIdx.x;
  const int j0 = blockIdx.y * PJSZ;
  for (int idx = tid; idx < K_B * PJSZ; idx += 256) {
    int k = idx / PJSZ, jj = idx % PJSZ;
    Vl[k][jj] = V[((size_t)n * K_B + k) * J_F + j0 + jj];
  }
  __syncthreads();
  const int i = blockIdx.x * 256 + tid;
  if (i >= I_F) return;
  float tr[K_B];
#pragma unroll
  for (int k = 0; k < K_B; ++k) tr[k] = T[((size_t)n * I_F + i) * 8 + k];
  const float4 w = ((const float4*)W)[i * 2 + n];
  float num[K_B] = {}, den[K_B] = {};
  const float2* Xa = X + i;
  const float2* Xb = X + (size_t)J_F * I_F + i;
  float* Pn = P + ((size_t)n * J_F + j0) * I_F + i;
#pragma unroll 4
  for (int jj = 0; jj < PJSZ; ++jj) {
    const size_t jo = (size_t)(j0 + jj) * I_F;
    float2 x0 = Xa[jo];
    float2 x1 = Xb[jo];
    float yr = w.x * x0.x - w.y * x0.y + w.z * x1.x - w.w * x1.y;
    float yi = w.x * x0.y + w.y * x0.x + w.z * x1.y + w.w * x1.x;
    float p = yr * yr + yi * yi;
    Pn[(size_t)jj * I_F] = p;
    float R = 0.f;
#pragma unroll
    for (int k = 0; k < K_B; ++k) R += tr[k] * Vl[k][jj];
    float a = p / (R * R);
    float b = 1.0f / R;
#pragma unroll
    for (int k = 0; k < K_B; ++k) { num[k] += a * Vl[k][jj]; den[k] += b * Vl[k][jj]; }
  }
  float* base = Tpart + (((size_t)n * PJT + blockIdx.y) * IB + i) * 16;
  *(float4*)(base + 0)  = make_float4(num[0], num[1], num[2], num[3]);
  *(float4*)(base + 4)  = make_float4(num[4], num[5], num[6], num[7]);
  *(float4*)(base + 8)  = make_float4(den[0], den[1], den[2], den[3]);
  *(float4*)(base + 12) = make_float4(den[4], den[5], den[6], den[7]);
}

// ---------------- finish T update from partials ----------------
__global__ __launch_bounds__(256) void k_t_finish(const float* __restrict__ Tpart,
                                                  float* __restrict__ T) {
  int t = blockIdx.x * 256 + threadIdx.x;
  if (t >= 2 * I_F * K_B) return;
  int n = t / (I_F * K_B);
  int r = t % (I_F * K_B);
  int i = r >> 3, k = r & 7;
  float num = 0.f, den = 0.f;
  const float* p = Tpart + (((size_t)n * PJT) * IB + i) * 16;
#pragma unroll 5
  for (int jt = 0; jt < PJT; ++jt) {
    num += p[(size_t)jt * IB * 16 + k];
    den += p[(size_t)jt * IB * 16 + 8 + k];
  }
  float told = T[t];
  T[t] = fmaxf(told * sqrtf(num / den), NMF_EPS);
}

// ------- V update: one block per (j,n), full reduction over i, in place -------
__global__ __launch_bounds__(256) void k_v_update(const float* __restrict__ P,
                                                  const float* __restrict__ T,
                                                  float* __restrict__ V) {
  const int j = blockIdx.x;
  const int n = blockIdx.y;
  const int tid = threadIdx.x;
  const float* Pn = P + ((size_t)n * J_F + j) * I_F;
  const float* Tn = T + (size_t)n * I_F * K_B;
  float vold[K_B];
#pragma unroll
  for (int k = 0; k < K_B; ++k) vold[k] = V[((size_t)n * K_B + k) * J_F + j];
  float num[K_B] = {}, den[K_B] = {};
  for (int i = tid; i < I_F; i += 256) {
    float p = Pn[i];
    const float4 ta = *(const float4*)&Tn[i * 8];
    const float4 tb = *(const float4*)&Tn[i * 8 + 4];
    float tk[K_B] = {ta.x, ta.y, ta.z, ta.w, tb.x, tb.y, tb.z, tb.w};
    float R = 0.f;
#pragma unroll
    for (int k = 0; k < K_B; ++k) R += tk[k] * vold[k];
    float a = p / (R * R);
    float b = 1.0f / R;
#pragma unroll
    for (int k = 0; k < K_B; ++k) { num[k] += a * tk[k]; den[k] += b * tk[k]; }
  }
  __shared__ float red[4][16];
  const int lane = tid & 63, wid = tid >> 6;
#pragma unroll
  for (int k = 0; k < K_B; ++k) {
    float a = num[k], b = den[k];
#pragma unroll
    for (int off = 32; off > 0; off >>= 1) {
      a += __shfl_xor(a, off, 64);
      b += __shfl_xor(b, off, 64);
    }
    if (lane == 0) { red[wid][k] = a; red[wid][8 + k] = b; }
  }
  __syncthreads();
  if (tid < 16) red[0][tid] = red[0][tid] + red[1][tid] + red[2][tid] + red[3][tid];
  __syncthreads();
  if (tid < 8) {
    float vo = V[((size_t)n * K_B + tid) * J_F + j];
    V[((size_t)n * K_B + tid) * J_F + j] =
        fmaxf(vo * sqrtf(red[0][tid] / red[0][8 + tid]), NMF_EPS);
  }
}

// -------- weighted covariance partials; one n per z-block --------
__global__ __launch_bounds__(256) void k_d_partial(const float2* __restrict__ X,
                                                   const float* __restrict__ T,
                                                   const float* __restrict__ V,
                                                   float* __restrict__ Dpart) {
  __shared__ float Vl[K_B][JCHSZ];
  const int n = blockIdx.z;
  const int tid = threadIdx.x;
  const int j0 = blockIdx.y * JCHSZ;
  for (int idx = tid; idx < K_B * JCHSZ; idx += 256) {
    int k = idx / JCHSZ, jj = idx % JCHSZ;
    Vl[k][jj] = V[((size_t)n * K_B + k) * J_F + j0 + jj];
  }
  __syncthreads();
  const int i = blockIdx.x * 256 + tid;
  if (i >= I_F) return;
  float tr[K_B];
#pragma unroll
  for (int k = 0; k < K_B; ++k) tr[k] = T[((size_t)n * I_F + i) * K_B + k];
  float a00 = 0.f, a11 = 0.f, a01r = 0.f, a01i = 0.f;
  const float2* Xa = X + i;
  const float2* Xb = X + (size_t)J_F * I_F + i;
#pragma unroll 4
  for (int jj = 0; jj < JCHSZ; ++jj) {
    const size_t jo = (size_t)(j0 + jj) * I_F;
    float R = 0.f;
#pragma unroll
    for (int k = 0; k < K_B; ++k) R += tr[k] * Vl[k][jj];
    float wv = 1.0f / (R + IP_EPS);
    float2 x0 = Xa[jo];
    float2 x1 = Xb[jo];
    a00 += wv * (x0.x * x0.x + x0.y * x0.y);
    a11 += wv * (x1.x * x1.x + x1.y * x1.y);
    a01r += wv * (x0.x * x1.x + x0.y * x1.y);
    a01i += wv * (x0.y * x1.x - x0.x * x1.y);
  }
  ((float4*)Dpart)[((size_t)n * JCH + blockIdx.y) * I_F + i] =
      make_float4(a00, a11, a01r, a01i);
}

// -------- combine D + sequential 2x2 complex solves (n=0 then n=1) --------
__global__ __launch_bounds__(256) void k_d_solve(const float* __restrict__ Dpart,
                                                 float* __restrict__ W) {
  const int i = blockIdx.x * 256 + threadIdx.x;
  if (i >= I_F) return;
  float4 wa = ((const float4*)W)[i * 2];
  float4 wb = ((const float4*)W)[i * 2 + 1];
  float w00r = wa.x, w00i = wa.y, w01r = wa.z, w01i = wa.w;
  float w10r = wb.x, w10i = wb.y, w11r = wb.z, w11i = wb.w;
  const float invJ = 1.0f / (float)J_F;
#pragma unroll
  for (int n = 0; n < 2; ++n) {
    float d00 = 0.f, d11 = 0.f, d01r = 0.f, d01i = 0.f;
    const float4* dp = (const float4*)Dpart + (size_t)n * JCH * I_F + i;
#pragma unroll 5
    for (int c = 0; c < JCH; ++c) {
      float4 d = dp[(size_t)c * I_F];
      d00 += d.x; d11 += d.y; d01r += d.z; d01i += d.w;
    }
    d00 = d00 * invJ + IP_EPS;
    d11 = d11 * invJ + IP_EPS;
    d01r *= invJ; d01i *= invJ;
    float A00r = w00r * d00 + (w01r * d01r + w01i * d01i);
    float A00i = w00i * d00 + (w01i * d01r - w01r * d01i);
    float A01r = (w00r * d01r - w00i * d01i) + w01r * d11;
    float A01i = (w00r * d01i + w00i * d01r) + w01i * d11;
    float A10r = w10r * d00 + (w11r * d01r + w11i * d01i);
    float A10i = w10i * d00 + (w11i * d01r - w11r * d01i);
    float A11r = (w10r * d01r - w10i * d01i) + w11r * d11;
    float A11i = (w10r * d01i + w10i * d01r) + w11i * d11;
    float detr = (A00r * A11r - A00i * A11i) - (A01r * A10r - A01i * A10i);
    float deti = (A00r * A11i + A00i * A11r) - (A01r * A10i + A01i * A10r);
    float idet = 1.0f / (detr * detr + deti * deti);
    float n0r, n0i, n1r, n1i;
    if (n == 0) { n0r = A11r; n0i = A11i; n1r = -A10r; n1i = -A10i; }
    else        { n0r = -A01r; n0i = -A01i; n1r = A00r; n1i = A00i; }
    float b0r = (n0r * detr + n0i * deti) * idet;
    float b0i = (n0i * detr - n0r * deti) * idet;
    float b1r = (n1r * detr + n1i * deti) * idet;
    float b1i = (n1i * detr - n1r * deti) * idet;
    float cr = d01r * b1r - d01i * b1i;
    float ci = d01r * b1i + d01i * b1r;
    float quad = d00 * (b0r * b0r + b0i * b0i) + d11 * (b1r * b1r + b1i * b1i)
               + 2.0f * (b0r * cr + b0i * ci);
    float s = 1.0f / sqrtf(quad + IP_EPS);
    if (n == 0) { w00r = b0r * s; w00i = -b0i * s; w01r = b1r * s; w01i = -b1i * s; }
    else        { w10r = b0r * s; w10i = -b0i * s; w11r = b1r * s; w11i = -b1i * s; }
  }
  ((float4*)W)[i * 2]     = make_float4(w00r, w00i, w01r, w01i);
  ((float4*)W)[i * 2 + 1] = make_float4(w10r, w10i, w11r, w11i);
}

// ---------------- final: out[n][j][i][2] = Y[i,n,j] ----------------
__global__ __launch_bounds__(256) void k_final(const float2* __restrict__ X,
                                               const float* __restrict__ W,
                                               float2* __restrict__ out) {
  const int i = blockIdx.x * 256 + threadIdx.x;
  if (i >= I_F) return;
  const float4 wa = ((const float4*)W)[i * 2];
  const float4 wb = ((const float4*)W)[i * 2 + 1];
  const int j0 = blockIdx.y * 8;
  const int jend = min(8, J_F - j0);
  for (int jj = 0; jj < jend; ++jj) {
    const int j = j0 + jj;
    float2 x0 = X[(size_t)j * I_F + i];
    float2 x1 = X[(size_t)(J_F + j) * I_F + i];
    float y0r = wa.x * x0.x - wa.y * x0.y + wa.z * x1.x - wa.w * x1.y;
    float y0i = wa.x * x0.y + wa.y * x0.x + wa.z * x1.y + wa.w * x1.x;
    out[(size_t)j * I_F + i] = make_float2(y0r, y0i);
    float y1r = wb.x * x0.x - wb.y * x0.y + wb.z * x1.x - wb.w * x1.y;
    float y1i = wb.x * x0.y + wb.y * x0.x + wb.z * x1.y + wb.w * x1.x;
    out[(size_t)(J_F + j) * I_F + i] = make_float2(y1r, y1i);
  }
}

extern "C" void kernel_launch(void* const* d_in, const int* in_sizes, int n_in,
                              void* d_out, int out_size, void* d_ws, size_t ws_size,
                              hipStream_t stream) {
  const float2* X = (const float2*)d_in[0];
  const float* T0 = (const float*)d_in[1];
  const float* V0 = (const float*)d_in[2];
  char* ws = (char*)d_ws;
  size_t off = 0;
  auto alloc = [&](size_t bytes) -> void* {
    void* p = ws + off;
    off = (off + bytes + 255) & ~(size_t)255;
    return p;
  };
  float* W = (float*)alloc((size_t)I_F * 8 * 4);
  float* T = (float*)alloc((size_t)2 * I_F * K_B * 4);
  float* V = (float*)alloc((size_t)2 * K_B * J_F * 4);
  float* P = (float*)alloc((size_t)2 * I_F * J_F * 4);
  // Tpart (14.75 MB) and Dpart (3.3 MB) have disjoint lifetimes -> share
  float* Scr = (float*)alloc((size_t)2 * PJT * IB * 16 * 4);
  float* Tpart = Scr;
  float* Dpart = Scr;

  k_init<<<128, 256, 0, stream>>>(T0, V0, T, V, W);
  for (int it = 0; it < N_IT; ++it) {
    k_P_T<<<dim3(9, PJT, 2), 256, 0, stream>>>(X, W, T, V, P, Tpart);
    k_t_finish<<<129, 256, 0, stream>>>(Tpart, T);
    k_v_update<<<dim3(J_F, 2), 256, 0, stream>>>(P, T, V);
    k_d_partial<<<dim3(9, JCH, 2), 256, 0, stream>>>(X, T, V, Dpart);
    k_d_solve<<<9, 256, 0, stream>>>(Dpart, W);
  }
  k_final<<<dim3(9, 250), 256, 0, stream>>>(X, W, (float2*)d_out);
}